// Round 1
// 174.143 us; speedup vs baseline: 1.0567x; 1.0567x over previous
//
#include <hip/hip_runtime.h>
#include <cstdint>
#include <cstddef>

// Problem shape (fixed by the reference setup_inputs)
#define MDIM 8192
#define KDIM 2048
#define NDIM 2048
#define QBLK 128
#define KB   (KDIM / QBLK)   // 16
#define NB   (NDIM / QBLK)   // 16

typedef float floatx4 __attribute__((ext_vector_type(4)));
typedef int   int4v   __attribute__((ext_vector_type(4)));
typedef int   int8v   __attribute__((ext_vector_type(8)));

#define AS1 __attribute__((address_space(1)))
#define AS3 __attribute__((address_space(3)))

// ---------------------------------------------------------------------------
// fp8 e4m3fn helpers (software, bit-exact) — used by cold paths + check
// ---------------------------------------------------------------------------
__device__ inline float e4m3_rne(float q) {     // RNE to fp8 grid, |q| <= 448
    float aq = fabsf(q);
    float r;
    if (aq < 0.015625f) {                        // subnormal: grid 2^-9
        r = rintf(aq * 512.0f) * 0.001953125f;
    } else {
        unsigned u = __float_as_uint(aq);
        unsigned rem = u & 0xFFFFFu;
        unsigned base = u & ~0xFFFFFu;
        unsigned inc = (rem > 0x80000u || (rem == 0x80000u && (u & 0x100000u))) ? 0x100000u : 0u;
        r = __uint_as_float(base + inc);
    }
    return q < 0.0f ? -r : r;
}

__device__ inline unsigned e4m3_encode(float r) {  // r exactly on fp8 grid
    unsigned u = __float_as_uint(r);
    unsigned s = (u >> 24) & 0x80u;
    float a = fabsf(r);
    if (a < 0.015625f) return s | (unsigned)(a * 512.0f + 0.25f);
    unsigned e = ((u >> 23) & 0xFFu) - 120u;       // 1..15
    unsigned m = (u >> 20) & 7u;
    return s | (e << 3) | m;
}

__device__ inline float e4m3_decode(unsigned b) {
    unsigned s = b >> 7, e = (b >> 3) & 0xFu, m = b & 7u;
    float v;
    if (e == 0) v = (float)m * 0.001953125f;
    else        v = __uint_as_float((e + 120u) << 23) * (float)(8 + m) * 0.125f;
    return s ? -v : v;
}

__device__ inline int is_expbyte(unsigned b) {   // plausible f32/bf16 hi byte for fp8-exact value
    unsigned e = b & 0x7Fu;
    return (e >= 0x3Bu && e <= 0x43u) || e == 0x00u;
}

// ---------------------------------------------------------------------------
// Workspace layout
//   xq  [M][K]  fp8 bytes            @ 0        (16 MB)
//   wq8 [N][K]  fp8 bytes            @ 16 MB    (4 MB)
//   xs  [M][KB] f32 act scales       @ 20 MB    (512 KB)
//   flag int                         @ 20.5 MB
// ---------------------------------------------------------------------------
#define XQ_OFF  0
#define WQ_OFF  ((size_t)MDIM * KDIM)
#define XS_OFF  (WQ_OFF + (size_t)NDIM * KDIM)
#define FL_OFF  (XS_OFF + (size_t)MDIM * KB * 4)

#define QXB ((MDIM * KB) / 8)          // 16384 act-quant blocks
#define DWB ((NDIM * KDIM / 8) / 256)  // 2048 weight blocks

// ---------------------------------------------------------------------------
// Prep: act quant -> fp8 bytes + scales (HW v_cvt_pk_fp8_f32 for RNE encode —
// bit-identical to the software path since the quotient is the same IEEE
// division); weight -> fp8 bytes (delivery-format classified inline per wave).
// ---------------------------------------------------------------------------
__global__ __launch_bounds__(256) void prep_kernel(const float* __restrict__ x,
                                                   const void* __restrict__ wq,
                                                   unsigned char* __restrict__ xq,
                                                   unsigned char* __restrict__ wq8,
                                                   float* __restrict__ xs,
                                                   int* __restrict__ flag) {
    const int tid = threadIdx.x;
    if (blockIdx.x == 0 && tid == 0) *flag = 0;

    if (blockIdx.x < QXB) {
        // ---- activation quant: one 32-lane group per (1,128) block ----
        const int g = tid >> 5;
        const int l = tid & 31;
        const size_t bi = (size_t)blockIdx.x * 8 + g;    // = m*KB + kb
        const size_t base = bi << 7;

        const float4 v = *(const float4*)(x + base + (size_t)l * 4);
        float a = fmaxf(fmaxf(fabsf(v.x), fabsf(v.y)), fmaxf(fabsf(v.z), fabsf(v.w)));
        a = fmaxf(a, __shfl_xor(a, 1));
        a = fmaxf(a, __shfl_xor(a, 2));
        a = fmaxf(a, __shfl_xor(a, 4));
        a = fmaxf(a, __shfl_xor(a, 8));
        a = fmaxf(a, __shfl_xor(a, 16));

        const float scale = fmaxf(a, 1e-12f) / 448.0f;
        if (l == 0) xs[bi] = scale;

        // exact IEEE divisions (same as reference), HW RNE pack to fp8
        const float q0 = v.x / scale, q1 = v.y / scale;
        const float q2 = v.z / scale, q3 = v.w / scale;
        int w = __builtin_amdgcn_cvt_pk_fp8_f32(q0, q1, 0, false);   // bits [15:0]
        w = __builtin_amdgcn_cvt_pk_fp8_f32(q2, q3, w, true);        // bits [31:16]
        *(unsigned*)(xq + base + (size_t)l * 4) = (unsigned)w;
    } else {
        // ---- weight repack to fp8 bytes ----
        const int lane = tid & 63;
        const unsigned pw = ((const unsigned*)wq)[lane];
        const unsigned long long m3 = __ballot(is_expbyte((pw >> 24) & 0xFFu));
        const unsigned long long m1 = __ballot(((pw >> 8) & 0xFFu) == 0u);
        const int f = (__popcll(m3) >= 56) ? ((__popcll(m1) >= 56) ? 2 : 1) : 0;

        const size_t idx = (size_t)(blockIdx.x - QXB) * 256 + tid;
        const size_t off = idx * 8;

        unsigned lo, hi;
        if (f == 2) {              // float32 upcast delivery
            const float4* p = (const float4*)((const float*)wq + off);
            const float4 a = p[0], b = p[1];
            lo = e4m3_encode(a.x) | (e4m3_encode(a.y) << 8) | (e4m3_encode(a.z) << 16) | (e4m3_encode(a.w) << 24);
            hi = e4m3_encode(b.x) | (e4m3_encode(b.y) << 8) | (e4m3_encode(b.z) << 16) | (e4m3_encode(b.w) << 24);
        } else if (f == 1) {       // bf16 upcast delivery
            const ushort4 h0 = *(const ushort4*)((const unsigned short*)wq + off);
            const ushort4 h1 = *(((const ushort4*)((const unsigned short*)wq + off)) + 1);
            lo = e4m3_encode(__uint_as_float((unsigned)h0.x << 16))
               | (e4m3_encode(__uint_as_float((unsigned)h0.y << 16)) << 8)
               | (e4m3_encode(__uint_as_float((unsigned)h0.z << 16)) << 16)
               | (e4m3_encode(__uint_as_float((unsigned)h0.w << 16)) << 24);
            hi = e4m3_encode(__uint_as_float((unsigned)h1.x << 16))
               | (e4m3_encode(__uint_as_float((unsigned)h1.y << 16)) << 8)
               | (e4m3_encode(__uint_as_float((unsigned)h1.z << 16)) << 16)
               | (e4m3_encode(__uint_as_float((unsigned)h1.w << 16)) << 24);
        } else {                   // already raw fp8 bytes
            const uint2 d = *(const uint2*)((const unsigned char*)wq + off);
            lo = d.x; hi = d.y;
        }
        *(uint2*)(wq8 + off) = make_uint2(lo, hi);
    }
}

// ---------------------------------------------------------------------------
// Primary GEMM: 256x256 tile, 8 waves (2M x 4N, each 128x64 output), MX fp8
// K=128 per MFMA (one quant block), double-buffered LDS + prefetch-next 2-phase
// loop (T3 minimum recipe: STAGE(t+1) issued BEFORE compute(t); one vmcnt(0)
// drain per K-step at the __syncthreads). Same XOR-swizzled 16B-chunk layout
// and MX fragment addressing as the verified 128x128 kernel. Per-row act
// scales staged transposed in LDS (broadcast reads). XCD-grouped tile map:
// the 8 n-tiles of each m-row land on one XCD -> A panel fetched once/XCD.
// ---------------------------------------------------------------------------
__global__ __launch_bounds__(512, 2) void gemm_mx_kernel(const unsigned char* __restrict__ Aq,
                                                         const unsigned char* __restrict__ Bq,
                                                         const float* __restrict__ xs,
                                                         const float* __restrict__ wsc,
                                                         float* __restrict__ C) {
    __shared__ unsigned char sA[2][256 * 128];   // 64 KB
    __shared__ unsigned char sB[2][256 * 128];   // 64 KB
    __shared__ float sxs[KB][256];               // 16 KB transposed act scales

    const int tid  = threadIdx.x;
    const int wave = tid >> 6;
    const int lane = tid & 63;
    const int lrow = lane & 15;
    const int lk   = lane >> 4;            // k-group (32 bytes each)
    const int wml  = (wave >> 2) * 128;    // wave m-offset in tile (2 waves in M)
    const int wnl  = (wave & 3) * 64;      // wave n-offset in tile (4 waves in N)

    // XCD-grouped bijective tile map: 256 blocks, XCD g (bid%8==g) gets the 32
    // tiles with m-rows {4g..4g+3} x all 8 n-cols -> A panels shared in-XCD L2.
    const int bid = blockIdx.x;
    const int lid = ((bid & 7) << 5) + (bid >> 3);
    const int m0  = (lid >> 3) * 256;
    const int n0  = (lid & 7) * 256;
    const int nb  = (n0 + wnl) >> 7;       // weight n-block of this wave (uniform)

    // staging: thread t, pass it -> row = it*64 + t/8, physical chunk = t&7
    // holding logical chunk (t&7)^(row&7); LDS dest linear at t*16 + it*8192.
    const int srow = tid >> 3;
    const int gck  = (tid & 7) ^ (srow & 7);
    const unsigned char* agp = Aq + (size_t)(m0 + srow) * KDIM + gck * 16;
    const unsigned char* bgp = Bq + (size_t)(n0 + srow) * KDIM + gck * 16;

#define STAGE(buf, kb_) do {                                                          \
    const size_t koff_ = (size_t)(kb_) * QBLK;                                        \
    _Pragma("unroll")                                                                 \
    for (int it = 0; it < 4; ++it)                                                    \
        __builtin_amdgcn_global_load_lds(                                             \
            (const AS1 void*)(agp + (size_t)(it * 64) * KDIM + koff_),                \
            (AS3 void*)(&sA[buf][0] + tid * 16 + it * 8192), 16, 0, 0);               \
    _Pragma("unroll")                                                                 \
    for (int it = 0; it < 4; ++it)                                                    \
        __builtin_amdgcn_global_load_lds(                                             \
            (const AS1 void*)(bgp + (size_t)(it * 64) * KDIM + koff_),                \
            (AS3 void*)(&sB[buf][0] + tid * 16 + it * 8192), 16, 0, 0);               \
} while (0)

    // one-time: stage act scales transposed (sxs[kb][row]) + first K-tile
    STAGE(0, 0);
    if (tid < 256) {
        const float4* xp = (const float4*)(xs + (size_t)(m0 + tid) * KB);
#pragma unroll
        for (int q = 0; q < 4; ++q) {
            const float4 v = xp[q];
            sxs[q * 4 + 0][tid] = v.x;
            sxs[q * 4 + 1][tid] = v.y;
            sxs[q * 4 + 2][tid] = v.z;
            sxs[q * 4 + 3][tid] = v.w;
        }
    }
    __syncthreads();   // drains vmcnt(0) + lgkmcnt(0): buf0 + sxs ready

    floatx4 acc[8][4] = {};
    const floatx4 zero = {0.f, 0.f, 0.f, 0.f};

    for (int kb = 0; kb < KB; ++kb) {            // 16 K-steps of 128
        const int cur = kb & 1;
        if (kb + 1 < KB) STAGE(cur ^ 1, kb + 1); // prefetch BEFORE compute

        // B fragments: logical bytes [lk*32, lk*32+32) of rows wnl+j*16+lrow
        int8v bf[4];
#pragma unroll
        for (int j = 0; j < 4; ++j) {
            const int Rb = wnl + j * 16 + lrow;
            const int d0 = (lk * 2) ^ (Rb & 7);
            const int d1 = (lk * 2 + 1) ^ (Rb & 7);
            int4v blo = *(const int4v*)(&sB[cur][0] + Rb * 128 + d0 * 16);
            int4v bhi = *(const int4v*)(&sB[cur][0] + Rb * 128 + d1 * 16);
            bf[j] = __builtin_shufflevector(blo, bhi, 0, 1, 2, 3, 4, 5, 6, 7);
        }
        const float wsk = wsc[nb * KB + kb];

#pragma unroll
        for (int i = 0; i < 8; ++i) {
            const int Ra = wml + i * 16 + lrow;
            const int c0 = (lk * 2) ^ (Ra & 7);
            const int c1 = (lk * 2 + 1) ^ (Ra & 7);
            int4v alo = *(const int4v*)(&sA[cur][0] + Ra * 128 + c0 * 16);
            int4v ahi = *(const int4v*)(&sA[cur][0] + Ra * 128 + c1 * 16);
            int8v af = __builtin_shufflevector(alo, ahi, 0, 1, 2, 3, 4, 5, 6, 7);

            // per-row combined scales (C/D row = lk*4 + r), broadcast LDS read
            const float4 xv = *(const float4*)(&sxs[kb][wml + i * 16 + lk * 4]);
            const float cs0 = xv.x * wsk, cs1 = xv.y * wsk;
            const float cs2 = xv.z * wsk, cs3 = xv.w * wsk;

#pragma unroll
            for (int j = 0; j < 4; ++j) {
                floatx4 blk = __builtin_amdgcn_mfma_scale_f32_16x16x128_f8f6f4(
                    af, bf[j], zero, 0, 0, 0, 0x7F7F7F7F, 0, 0x7F7F7F7F);
                acc[i][j][0] += cs0 * blk[0];
                acc[i][j][1] += cs1 * blk[1];
                acc[i][j][2] += cs2 * blk[2];
                acc[i][j][3] += cs3 * blk[3];
            }
        }
        __syncthreads();   // vmcnt(0): prefetched tile landed; LDS reads done
    }
#undef STAGE

    // Epilogue: col = lane&15, row = lk*4 + r
#pragma unroll
    for (int i = 0; i < 8; ++i) {
        const int row0 = m0 + wml + i * 16 + lk * 4;
#pragma unroll
        for (int r = 0; r < 4; ++r) {
            float* cp = C + (size_t)(row0 + r) * NDIM + n0 + wnl + lrow;
#pragma unroll
            for (int j = 0; j < 4; ++j)
                cp[j * 16] = acc[i][j][r];
        }
    }
}

// ---------------------------------------------------------------------------
// Check: recompute 64 sampled outputs exactly from the quantized bytes; set
// flag if the MX GEMM result deviates (NaN-safe compare).
// ---------------------------------------------------------------------------
__global__ __launch_bounds__(256) void check_kernel(const unsigned char* __restrict__ xq,
                                                    const unsigned char* __restrict__ wq8,
                                                    const float* __restrict__ xs,
                                                    const float* __restrict__ wsc,
                                                    const float* __restrict__ y,
                                                    int* __restrict__ flag) {
    const int s = blockIdx.x;
    const int m = (s * 1237 + 11) & (MDIM - 1);
    const int n = (s * 389 + 7) & (NDIM - 1);
    const int tid = threadIdx.x;
    const int k0 = tid * 8;
    const int kb = k0 >> 7;

    const unsigned char* xp = xq + (size_t)m * KDIM + k0;
    const unsigned char* wp = wq8 + (size_t)n * KDIM + k0;
    float dot = 0.f;
#pragma unroll
    for (int i = 0; i < 8; ++i)
        dot += e4m3_decode(xp[i]) * e4m3_decode(wp[i]);
    float part = dot * xs[m * KB + kb] * wsc[(n >> 7) * KB + kb];

#pragma unroll
    for (int o = 32; o > 0; o >>= 1) part += __shfl_down(part, o);
    __shared__ float wsum[4];
    if ((tid & 63) == 0) wsum[tid >> 6] = part;
    __syncthreads();
    if (tid == 0) {
        const float tot = wsum[0] + wsum[1] + wsum[2] + wsum[3];
        const float d = tot - y[(size_t)m * NDIM + n];
        if (!(fabsf(d) <= 0.05f)) atomicOr(flag, 1);
    }
}

// ---------------------------------------------------------------------------
// Fallback GEMM (flag-guarded): non-scaled mfma_f32_16x16x32_fp8_fp8 (m145-
// verified k-geometry: k = (lane>>4)*8 + byte) + identical VALU scale fixup.
// Only runs if the MX layout check failed. Unchanged from the verified kernel.
// ---------------------------------------------------------------------------
__global__ __launch_bounds__(256, 2) void gemm_fb_kernel(const unsigned char* __restrict__ Aq,
                                                         const unsigned char* __restrict__ Bq,
                                                         const float* __restrict__ xs,
                                                         const float* __restrict__ wsc,
                                                         float* __restrict__ C,
                                                         const int* __restrict__ flag) {
    if (*flag == 0) return;

    __shared__ unsigned char sA[128 * 128];
    __shared__ unsigned char sB[128 * 128];

    const int tid  = threadIdx.x;
    const int wave = tid >> 6;
    const int lane = tid & 63;
    const int lrow = lane & 15;
    const int lk   = lane >> 4;
    const int wm   = (wave & 1) * 64;
    const int wn   = (wave >> 1) * 64;
    const int m0   = blockIdx.y * 128;
    const int n0   = blockIdx.x * 128;
    const int nb   = n0 >> 7;

    const int srow = tid >> 3;
    const int gck  = (tid & 7) ^ (srow & 7);
    const unsigned char* agp = Aq + (size_t)(m0 + srow) * KDIM + gck * 16;
    const unsigned char* bgp = Bq + (size_t)(n0 + srow) * KDIM + gck * 16;

    floatx4 acc[4][4] = {};

    for (int kb = 0; kb < KB; ++kb) {
        const size_t koff = (size_t)kb * QBLK;
        __syncthreads();
#pragma unroll
        for (int it = 0; it < 4; ++it)
            __builtin_amdgcn_global_load_lds(
                (const AS1 void*)(agp + (size_t)(it * 32) * KDIM + koff),
                (AS3 void*)(sA + tid * 16 + it * 4096), 16, 0, 0);
#pragma unroll
        for (int it = 0; it < 4; ++it)
            __builtin_amdgcn_global_load_lds(
                (const AS1 void*)(bgp + (size_t)(it * 32) * KDIM + koff),
                (AS3 void*)(sB + tid * 16 + it * 4096), 16, 0, 0);
        __syncthreads();

        floatx4 blk[4][4] = {};
#pragma unroll
        for (int ks = 0; ks < 4; ++ks) {        // K = 32 per MFMA
            long a8[4], b8[4];
            const int lc = ks * 2 + (lk >> 1);  // logical chunk of this 8B frag
            const int bo = (lk & 1) * 8;        // byte offset within chunk
#pragma unroll
            for (int i = 0; i < 4; ++i) {
                const int Ra = wm + i * 16 + lrow;
                a8[i] = *(const long*)(sA + Ra * 128 + (lc ^ (Ra & 7)) * 16 + bo);
                const int Rb = wn + i * 16 + lrow;
                b8[i] = *(const long*)(sB + Rb * 128 + (lc ^ (Rb & 7)) * 16 + bo);
            }
#pragma unroll
            for (int i = 0; i < 4; ++i)
#pragma unroll
                for (int j = 0; j < 4; ++j)
                    blk[i][j] = __builtin_amdgcn_mfma_f32_16x16x32_fp8_fp8(a8[i], b8[j], blk[i][j], 0, 0, 0);
        }

        const float wsk = wsc[nb * KB + kb];
#pragma unroll
        for (int i = 0; i < 4; ++i) {
            float cs[4];
#pragma unroll
            for (int r = 0; r < 4; ++r)
                cs[r] = xs[(size_t)(m0 + wm + i * 16 + lk * 4 + r) * KB + kb] * wsk;
#pragma unroll
            for (int j = 0; j < 4; ++j)
#pragma unroll
                for (int r = 0; r < 4; ++r)
                    acc[i][j][r] += cs[r] * blk[i][j][r];
        }
    }

#pragma unroll
    for (int i = 0; i < 4; ++i) {
        const int row0 = m0 + wm + i * 16 + lk * 4;
#pragma unroll
        for (int r = 0; r < 4; ++r) {
            float* cp = C + (size_t)(row0 + r) * NDIM + n0 + wn + lrow;
#pragma unroll
            for (int j = 0; j < 4; ++j)
                cp[j * 16] = acc[i][j][r];
        }
    }
}

// ---------------------------------------------------------------------------
extern "C" void kernel_launch(void* const* d_in, const int* in_sizes, int n_in,
                              void* d_out, int out_size, void* d_ws, size_t ws_size,
                              hipStream_t stream) {
    const float* x      = (const float*)d_in[0];
    const void* wq      = d_in[1];
    const float* wscale = (const float*)d_in[2];
    float* y            = (float*)d_out;

    unsigned char* xq  = (unsigned char*)d_ws + XQ_OFF;
    unsigned char* wq8 = (unsigned char*)d_ws + WQ_OFF;
    float* xs          = (float*)((unsigned char*)d_ws + XS_OFF);
    int* flag          = (int*)((unsigned char*)d_ws + FL_OFF);

    prep_kernel<<<QXB + DWB, 256, 0, stream>>>(x, wq, xq, wq8, xs, flag);
    gemm_mx_kernel<<<(MDIM / 256) * (NDIM / 256), 512, 0, stream>>>(xq, wq8, xs, wscale, y);
    check_kernel<<<64, 256, 0, stream>>>(xq, wq8, xs, wscale, y, flag);
    gemm_fb_kernel<<<dim3(NDIM / 128, MDIM / 128), 256, 0, stream>>>(xq, wq8, xs, wscale, y, flag);
}